// Round 1
// baseline (1456.626 us; speedup 1.0000x reference)
//
#include <hip/hip_runtime.h>
#include <math.h>

#define NN 50000
#define NE 800000
#define HD 128
#define NH 8
#define DO 16

// ---------------- atomic float max (int-trick) ----------------
__device__ __forceinline__ void atomicMaxFloat(float* addr, float val) {
    if (val >= 0.0f) {
        atomicMax((int*)addr, __float_as_int(val));
    } else {
        atomicMin((unsigned int*)addr, __float_as_uint(val));
    }
}

// ---------------- init: zeros + m = -inf ----------------
__global__ void init_kernel(float* __restrict__ zero_ptr, long nz,
                            unsigned int* __restrict__ minf_ptr, long nm) {
    long i = (long)blockIdx.x * blockDim.x + threadIdx.x;
    long stride = (long)gridDim.x * blockDim.x;
    for (long j = i; j < nz; j += stride) zero_ptr[j] = 0.0f;
    for (long j = i; j < nm; j += stride) minf_ptr[j] = 0xFF800000u; // -inf
}

// ---------------- hf = nfeat @ W_fc  (128x128 W in LDS) ----------------
__global__ __launch_bounds__(256) void gemm_fc_kernel(const float* __restrict__ A,
                                                      const float* __restrict__ W,
                                                      float* __restrict__ out) {
    __shared__ float sW[HD * HD];
    __shared__ float sA[2][HD];
    for (int i = threadIdx.x; i < HD * HD; i += 256) sW[i] = W[i];
    __syncthreads();
    int col = threadIdx.x & 127;
    int rs  = threadIdx.x >> 7;
    for (int row0 = blockIdx.x * 2; row0 < NN; row0 += gridDim.x * 2) {
        int row = row0 + rs;
        __syncthreads();
        sA[rs][col] = (row < NN) ? A[(size_t)row * HD + col] : 0.0f;
        __syncthreads();
        float acc = 0.0f;
#pragma unroll 16
        for (int k = 0; k < HD; ++k) acc += sA[rs][k] * sW[k * HD + col];
        if (row < NN) out[(size_t)row * HD + col] = acc;
    }
}

// ---------------- el/er = einsum(h, attn_l/r) ----------------
__global__ void attn_proj_kernel(const float* __restrict__ hf,
                                 const float* __restrict__ attn_l,
                                 const float* __restrict__ attn_r,
                                 float* __restrict__ el, float* __restrict__ er) {
    int idx = blockIdx.x * blockDim.x + threadIdx.x; // n*8+h
    if (idx >= NN * NH) return;
    int h = idx & 7;
    const float* hrow = hf + (size_t)(idx >> 3) * HD + h * DO;
    float sl = 0.0f, sr = 0.0f;
#pragma unroll
    for (int d = 0; d < DO; ++d) {
        float v = hrow[d];
        sl += v * attn_l[h * DO + d];
        sr += v * attn_r[h * DO + d];
    }
    el[idx] = sl;
    er[idx] = sr;
}

// ---------------- edge pass 1: segment max + indeg ----------------
__global__ void edge_max_kernel(const int* __restrict__ src, const int* __restrict__ dst,
                                const float* __restrict__ el, const float* __restrict__ er,
                                float* __restrict__ m, float* __restrict__ indeg) {
    int idx = blockIdx.x * blockDim.x + threadIdx.x; // e*8+h
    if (idx >= NE * NH) return;
    int e = idx >> 3, h = idx & 7;
    int s = src[e], d = dst[e];
    float x = el[s * NH + h] + er[d * NH + h];
    x = x > 0.0f ? x : 0.2f * x;            // leaky_relu(0.2)
    atomicMaxFloat(&m[d * NH + h], x);
    if (h == 0) atomicAdd(&indeg[d], 1.0f);
}

// ---------------- edge pass 2: softmax denominator ----------------
__global__ void edge_denom_kernel(const int* __restrict__ src, const int* __restrict__ dst,
                                  const float* __restrict__ el, const float* __restrict__ er,
                                  const float* __restrict__ m, float* __restrict__ denom) {
    int idx = blockIdx.x * blockDim.x + threadIdx.x; // e*8+h
    if (idx >= NE * NH) return;
    int e = idx >> 3, h = idx & 7;
    int s = src[e], d = dst[e];
    float x = el[s * NH + h] + er[d * NH + h];
    x = x > 0.0f ? x : 0.2f * x;
    atomicAdd(&denom[d * NH + h], __expf(x - m[d * NH + h]));
}

// ---------------- edge pass 3: weighted aggregate + efeat aggregate ----------------
__global__ void edge_agg_kernel(const int* __restrict__ src, const int* __restrict__ dst,
                                const float* __restrict__ hf, const float* __restrict__ efeat,
                                const float* __restrict__ el, const float* __restrict__ er,
                                const float* __restrict__ m, const float* __restrict__ denom,
                                float* __restrict__ agg, float* __restrict__ aggE) {
    long idx = (long)blockIdx.x * blockDim.x + threadIdx.x; // e*128+c
    if (idx >= (long)NE * HD) return;
    int e = (int)(idx >> 7);
    int c = (int)(idx & 127);
    int h = c >> 4;
    int s = src[e], d = dst[e];
    float x = el[s * NH + h] + er[d * NH + h];
    x = x > 0.0f ? x : 0.2f * x;
    float a = __expf(x - m[d * NH + h]) / denom[d * NH + h];
    atomicAdd(&agg[(size_t)d * HD + c], a * hf[(size_t)s * HD + c]);
    atomicAdd(&aggE[(size_t)d * HD + c], efeat[idx]);
}

// ---------------- final: h_e GEMM + combine ----------------
__global__ __launch_bounds__(256) void final_kernel(const float* __restrict__ aggE,
                                                    const float* __restrict__ W_e,
                                                    const float* __restrict__ agg,
                                                    const float* __restrict__ hf,
                                                    const float* __restrict__ bias,
                                                    const float* __restrict__ b_e,
                                                    const float* __restrict__ indeg,
                                                    float* __restrict__ out) {
    __shared__ float sW[HD * HD];
    __shared__ float sA[2][HD];
    for (int i = threadIdx.x; i < HD * HD; i += 256) sW[i] = W_e[i];
    __syncthreads();
    int col = threadIdx.x & 127;
    int rs  = threadIdx.x >> 7;
    for (int row0 = blockIdx.x * 2; row0 < NN; row0 += gridDim.x * 2) {
        int row = row0 + rs;
        __syncthreads();
        sA[rs][col] = (row < NN) ? aggE[(size_t)row * HD + col] : 0.0f;
        __syncthreads();
        float acc = 0.0f;
#pragma unroll 16
        for (int k = 0; k < HD; ++k) acc += sA[rs][k] * sW[k * HD + col];
        if (row < NN) {
            float deg = indeg[row];
            float he  = (acc + deg * b_e[col]) / fmaxf(deg, 1.0f);
            out[(size_t)row * HD + col] = agg[(size_t)row * HD + col] + bias[col]
                                        + hf[(size_t)row * HD + col] / (deg + 1.0f) + he;
        }
    }
}

extern "C" void kernel_launch(void* const* d_in, const int* in_sizes, int n_in,
                              void* d_out, int out_size, void* d_ws, size_t ws_size,
                              hipStream_t stream) {
    const float* nfeat  = (const float*)d_in[0];
    const float* efeat  = (const float*)d_in[1];
    const int*   src    = (const int*)d_in[2];
    const int*   dst    = (const int*)d_in[3];
    const float* W_fc   = (const float*)d_in[4];
    const float* attn_l = (const float*)d_in[5];
    const float* attn_r = (const float*)d_in[6];
    const float* bias   = (const float*)d_in[7];
    const float* W_e    = (const float*)d_in[8];
    const float* b_e    = (const float*)d_in[9];
    float* out = (float*)d_out;

    // workspace layout (floats):
    // hf[NN*128] | agg[NN*128] aggE[NN*128] denom[NN*8] indeg[NN] (zeroed, contiguous)
    // | el[NN*8] er[NN*8] | m[NN*8] (-inf)
    float* ws = (float*)d_ws;
    size_t o = 0;
    float* hf    = ws + o; o += (size_t)NN * HD;
    float* agg   = ws + o; o += (size_t)NN * HD;
    float* aggE  = ws + o; o += (size_t)NN * HD;
    float* denom = ws + o; o += (size_t)NN * NH;
    float* indeg = ws + o; o += (size_t)NN;
    float* el    = ws + o; o += (size_t)NN * NH;
    float* er    = ws + o; o += (size_t)NN * NH;
    float* m     = ws + o; o += (size_t)NN * NH;

    const long nz = (long)NN * (HD + HD + NH + 1); // agg..indeg contiguous
    const long nm = (long)NN * NH;

    init_kernel<<<4096, 256, 0, stream>>>(agg, nz, (unsigned int*)m, nm);

    gemm_fc_kernel<<<1024, 256, 0, stream>>>(nfeat, W_fc, hf);

    attn_proj_kernel<<<(NN * NH + 255) / 256, 256, 0, stream>>>(hf, attn_l, attn_r, el, er);

    edge_max_kernel<<<(NE * NH + 255) / 256, 256, 0, stream>>>(src, dst, el, er, m, indeg);

    edge_denom_kernel<<<(NE * NH + 255) / 256, 256, 0, stream>>>(src, dst, el, er, m, denom);

    {
        long total = (long)NE * HD;
        int blocks = (int)((total + 255) / 256);
        edge_agg_kernel<<<blocks, 256, 0, stream>>>(src, dst, hf, efeat, el, er, m, denom,
                                                    agg, aggE);
    }

    final_kernel<<<1024, 256, 0, stream>>>(aggE, W_e, agg, hf, bias, b_e, indeg, out);
}

// Round 2
// 1014.821 us; speedup vs baseline: 1.4354x; 1.4354x over previous
//
#include <hip/hip_runtime.h>
#include <math.h>

#define NN 50000
#define NE 800000
#define HD 128
#define NH 8
#define DO 16
#define NEG_BIG -3.0e38f

// ---------------- init: zero degree counters ----------------
__global__ void init_kernel(int* __restrict__ indeg) {
    int i = blockIdx.x * blockDim.x + threadIdx.x;
    if (i < NN) indeg[i] = 0;
}

// ---------------- count in-degrees ----------------
__global__ void count_deg_kernel(const int* __restrict__ dst, int* __restrict__ indeg) {
    int e = blockIdx.x * blockDim.x + threadIdx.x;
    if (e < NE) atomicAdd(&indeg[dst[e]], 1);
}

// ---------------- exclusive scan (single block, 1024 threads) ----------------
__global__ __launch_bounds__(1024) void scan_kernel(const int* __restrict__ indeg,
                                                    int* __restrict__ offsets,
                                                    int* __restrict__ cursor) {
    __shared__ int part[1024];
    const int t = threadIdx.x;
    const int CH = (NN + 1023) / 1024; // 49
    int b = t * CH, e = min(b + CH, NN);
    int s = 0;
    for (int i = b; i < e; ++i) s += indeg[i];
    part[t] = s;
    __syncthreads();
    for (int off = 1; off < 1024; off <<= 1) {
        int v = (t >= off) ? part[t - off] : 0;
        __syncthreads();
        part[t] += v;
        __syncthreads();
    }
    int base = (t == 0) ? 0 : part[t - 1];
    for (int i = b; i < e; ++i) {
        offsets[i] = base;
        cursor[i] = base;
        base += indeg[i];
    }
    if (t == 1023) offsets[NN] = base;
}

// ---------------- scatter edges into CSR order ----------------
__global__ void scatter_kernel(const int* __restrict__ src, const int* __restrict__ dst,
                               int* __restrict__ cursor, int2* __restrict__ sorted) {
    int e = blockIdx.x * blockDim.x + threadIdx.x;
    if (e < NE) {
        int d = dst[e];
        int pos = atomicAdd(&cursor[d], 1);
        sorted[pos] = make_int2(src[e], e);
    }
}

// ---------------- hf = nfeat @ W_fc  (128x128 W in LDS) ----------------
__global__ __launch_bounds__(256) void gemm_fc_kernel(const float* __restrict__ A,
                                                      const float* __restrict__ W,
                                                      float* __restrict__ out) {
    __shared__ float sW[HD * HD];
    __shared__ float sA[2][HD];
    for (int i = threadIdx.x; i < HD * HD; i += 256) sW[i] = W[i];
    __syncthreads();
    int col = threadIdx.x & 127;
    int rs  = threadIdx.x >> 7;
    for (int row0 = blockIdx.x * 2; row0 < NN; row0 += gridDim.x * 2) {
        int row = row0 + rs;
        __syncthreads();
        sA[rs][col] = (row < NN) ? A[(size_t)row * HD + col] : 0.0f;
        __syncthreads();
        float acc = 0.0f;
#pragma unroll 16
        for (int k = 0; k < HD; ++k) acc += sA[rs][k] * sW[k * HD + col];
        if (row < NN) out[(size_t)row * HD + col] = acc;
    }
}

// ---------------- el/er = einsum(h, attn_l/r) ----------------
__global__ void attn_proj_kernel(const float* __restrict__ hf,
                                 const float* __restrict__ attn_l,
                                 const float* __restrict__ attn_r,
                                 float* __restrict__ el, float* __restrict__ er) {
    int idx = blockIdx.x * blockDim.x + threadIdx.x; // n*8+h
    if (idx >= NN * NH) return;
    int h = idx & 7;
    const float* hrow = hf + (size_t)(idx >> 3) * HD + h * DO;
    float sl = 0.0f, sr = 0.0f;
#pragma unroll
    for (int d = 0; d < DO; ++d) {
        float v = hrow[d];
        sl += v * attn_l[h * DO + d];
        sr += v * attn_r[h * DO + d];
    }
    el[idx] = sl;
    er[idx] = sr;
}

// ---------------- fused per-node GAT: one wave per node, no atomics ----------------
__global__ __launch_bounds__(256) void node_kernel(
    const int2* __restrict__ sorted, const int* __restrict__ offsets,
    const float* __restrict__ hf, const float* __restrict__ efeat,
    const float* __restrict__ el, const float* __restrict__ er,
    const float* __restrict__ W_e, const float* __restrict__ bias,
    const float* __restrict__ b_e, float* __restrict__ out)
{
    int wv   = threadIdx.x >> 6;
    int lane = threadIdx.x & 63;
    int node = blockIdx.x * 4 + wv;
    if (node >= NN) return;
    int beg = offsets[node];
    int end = offsets[node + 1];

    // ---- pass 1: online softmax stats; lane = esub*8 + h ----
    int h = lane & 7;
    float er_h = er[node * NH + h];
    float m = NEG_BIG, ssum = 0.0f;
    for (int i = beg + (lane >> 3); i < end; i += 8) {
        int s = sorted[i].x;
        float x = el[s * NH + h] + er_h;
        x = x > 0.0f ? x : 0.2f * x;
        if (x > m) { ssum = ssum * __expf(m - x) + 1.0f; m = x; }
        else        ssum += __expf(x - m);
    }
    // combine (m,ssum) across the 8 edge-subsets per head (xor 8,16,32)
#pragma unroll
    for (int off = 8; off < 64; off <<= 1) {
        float mo = __shfl_xor(m, off);
        float so = __shfl_xor(ssum, off);
        float mn = fmaxf(m, mo);
        ssum = ssum * __expf(m - mn) + so * __expf(mo - mn);
        m = mn;
    }
    float r = ssum > 0.0f ? 1.0f / ssum : 0.0f;

    // ---- pass 2: weighted hf gather + efeat sum, cols c1=lane, c2=lane+64 ----
    int h1 = lane >> 4;      // head of col c1
    int h2 = h1 + 4;         // head of col c2
    float m1 = __shfl(m, h1), r1 = __shfl(r, h1);
    float m2 = __shfl(m, h2), r2 = __shfl(r, h2);
    float er1 = er[node * NH + h1];
    float er2 = er[node * NH + h2];

    float acc0 = 0.0f, acc1 = 0.0f, ea0 = 0.0f, ea1 = 0.0f;
#pragma unroll 2
    for (int i = beg; i < end; ++i) {
        int2 se = sorted[i];
        int s = se.x;
        size_t eb = (size_t)se.y * HD;
        float x1 = el[s * NH + h1] + er1; x1 = x1 > 0.0f ? x1 : 0.2f * x1;
        float x2 = el[s * NH + h2] + er2; x2 = x2 > 0.0f ? x2 : 0.2f * x2;
        float w1 = __expf(x1 - m1) * r1;
        float w2 = __expf(x2 - m2) * r2;
        acc0 += w1 * hf[(size_t)s * HD + lane];
        acc1 += w2 * hf[(size_t)s * HD + lane + 64];
        ea0 += efeat[eb + lane];
        ea1 += efeat[eb + lane + 64];
    }

    // ---- epilogue: he = (eacc @ W_e + deg*b_e)/max(deg,1), fused combine ----
    float we0 = 0.0f, we1 = 0.0f;
#pragma unroll 8
    for (int k = 0; k < 64; ++k) {
        float ek = __shfl(ea0, k);
        we0 += ek * W_e[k * HD + lane];
        we1 += ek * W_e[k * HD + lane + 64];
    }
#pragma unroll 8
    for (int k = 0; k < 64; ++k) {
        float ek = __shfl(ea1, k);
        we0 += ek * W_e[(k + 64) * HD + lane];
        we1 += ek * W_e[(k + 64) * HD + lane + 64];
    }
    float deg  = (float)(end - beg);
    float rdeg = 1.0f / fmaxf(deg, 1.0f);
    float rskip = 1.0f / (deg + 1.0f);
    size_t o = (size_t)node * HD;
    out[o + lane]      = acc0 + bias[lane]      + hf[o + lane]      * rskip + (we0 + deg * b_e[lane])      * rdeg;
    out[o + lane + 64] = acc1 + bias[lane + 64] + hf[o + lane + 64] * rskip + (we1 + deg * b_e[lane + 64]) * rdeg;
}

extern "C" void kernel_launch(void* const* d_in, const int* in_sizes, int n_in,
                              void* d_out, int out_size, void* d_ws, size_t ws_size,
                              hipStream_t stream) {
    const float* nfeat  = (const float*)d_in[0];
    const float* efeat  = (const float*)d_in[1];
    const int*   src    = (const int*)d_in[2];
    const int*   dst    = (const int*)d_in[3];
    const float* W_fc   = (const float*)d_in[4];
    const float* attn_l = (const float*)d_in[5];
    const float* attn_r = (const float*)d_in[6];
    const float* bias   = (const float*)d_in[7];
    const float* W_e    = (const float*)d_in[8];
    const float* b_e    = (const float*)d_in[9];
    float* out = (float*)d_out;

    // workspace layout
    float* ws = (float*)d_ws;
    size_t o = 0;
    float* hf      = ws + o; o += (size_t)NN * HD;       // 6.4M
    float* el      = ws + o; o += (size_t)NN * NH;       // 400K
    float* er      = ws + o; o += (size_t)NN * NH;       // 400K
    int*   indeg   = (int*)(ws + o); o += NN;            // 50K
    int*   offsets = (int*)(ws + o); o += NN + 1;
    int*   cursor  = (int*)(ws + o); o += NN;
    // align to 8 bytes for int2
    o = (o + 1) & ~(size_t)1;
    int2*  sorted  = (int2*)(ws + o); o += (size_t)NE * 2; // 1.6M ints
    // total ~36 MB

    init_kernel<<<(NN + 255) / 256, 256, 0, stream>>>(indeg);
    count_deg_kernel<<<(NE + 255) / 256, 256, 0, stream>>>(dst, indeg);
    scan_kernel<<<1, 1024, 0, stream>>>(indeg, offsets, cursor);
    scatter_kernel<<<(NE + 255) / 256, 256, 0, stream>>>(src, dst, cursor, sorted);

    gemm_fc_kernel<<<1024, 256, 0, stream>>>(nfeat, W_fc, hf);
    attn_proj_kernel<<<(NN * NH + 255) / 256, 256, 0, stream>>>(hf, attn_l, attn_r, el, er);

    node_kernel<<<(NN + 3) / 4, 256, 0, stream>>>(sorted, offsets, hf, efeat,
                                                  el, er, W_e, bias, b_e, out);
}